// Round 6
// baseline (426.473 us; speedup 1.0000x reference)
//
#include <hip/hip_runtime.h>

#define ENT_GRID 16
#define ENT_DIM  64
#define EMB      1024   // ENT_GRID * ENT_DIM
#define LN_EPS   1e-5f

__device__ __forceinline__ float dot4(float4 a, float4 b) {
    return a.x * b.x + a.y * b.y + a.z * b.z + a.w * b.w;
}

// One WAVE per batch row; lane l owns the 16 contiguous outputs 16l..16l+15.
// All 16 share e-block d = l (since i>>4 == l), so the matmul needs zero
// cross-lane traffic. LayerNorm reduce = one wave64 shfl butterfly.
// No LDS, no barriers, no sort. 4 rows per 256-thread block.
__global__ __launch_bounds__(256, 7)
void wproj_wave_kernel(const float* __restrict__ ent_emb,
                       const int*   __restrict__ proj_ids,
                       const float* __restrict__ rel_tran,
                       const float* __restrict__ rel_bias,
                       const float* __restrict__ ln_w,
                       const float* __restrict__ ln_b,
                       float* __restrict__ out, int B) {
    const int gw   = (blockIdx.x * blockDim.x + threadIdx.x) >> 6;  // global wave = row
    if (gw >= B) return;
    const int lane = threadIdx.x & 63;
    const int b    = gw;

    const long long r = (long long)proj_ids[b];

    // lane-private pointers
    const float4* __restrict__ tr4 = reinterpret_cast<const float4*>(
        rel_tran + (size_t)r * (ENT_DIM * ENT_GRID * ENT_GRID) + (size_t)lane * 256);
    const float4* __restrict__ bi4 = reinterpret_cast<const float4*>(
        rel_bias + (size_t)r * EMB + lane * 16);
    const float4* __restrict__ e4 = reinterpret_cast<const float4*>(
        ent_emb + (size_t)b * EMB + lane * 16);

    // this lane's e-block (16 floats), shared by all 16 of its outputs
    const float4 e0 = e4[0], e1 = e4[1], e2 = e4[2], e3 = e4[3];

    float acc[16];
    float s = 0.0f, ss = 0.0f;

    // 16 outputs: output k uses tran row (16l+k) = 4 consecutive float4s
#pragma unroll
    for (int kk = 0; kk < 4; ++kk) {           // group of 4 outputs
        const float4 bv = bi4[kk];
#pragma unroll
        for (int k = 0; k < 4; ++k) {          // output kk*4+k
            const float4 a0 = tr4[(kk * 4 + k) * 4 + 0];
            const float4 a1 = tr4[(kk * 4 + k) * 4 + 1];
            const float4 a2 = tr4[(kk * 4 + k) * 4 + 2];
            const float4 a3 = tr4[(kk * 4 + k) * 4 + 3];
            float v = (k == 0) ? bv.x : (k == 1) ? bv.y : (k == 2) ? bv.z : bv.w;
            v += dot4(a0, e0) + dot4(a1, e1) + dot4(a2, e2) + dot4(a3, e3);
            acc[kk * 4 + k] = v;
            s  += v;
            ss += v * v;
        }
    }

    // wave64 butterfly: every lane ends with the full row sums
#pragma unroll
    for (int off = 32; off > 0; off >>= 1) {
        s  += __shfl_xor(s, off, 64);
        ss += __shfl_xor(ss, off, 64);
    }
    const float mu   = s  * (1.0f / (float)EMB);
    const float var  = ss * (1.0f / (float)EMB) - mu * mu;
    const float rstd = rsqrtf(var + LN_EPS);

    const float4* __restrict__ lw4 = reinterpret_cast<const float4*>(ln_w + lane * 16);
    const float4* __restrict__ lb4 = reinterpret_cast<const float4*>(ln_b + lane * 16);
    float4* __restrict__ o4 = reinterpret_cast<float4*>(out + (size_t)b * EMB + lane * 16);

#pragma unroll
    for (int kk = 0; kk < 4; ++kk) {
        const float4 w = lw4[kk];
        const float4 bb = lb4[kk];
        float4 o;
        o.x = (acc[kk * 4 + 0] - mu) * rstd * w.x + bb.x;
        o.y = (acc[kk * 4 + 1] - mu) * rstd * w.y + bb.y;
        o.z = (acc[kk * 4 + 2] - mu) * rstd * w.z + bb.z;
        o.w = (acc[kk * 4 + 3] - mu) * rstd * w.w + bb.w;
        o4[kk] = o;
    }
}

extern "C" void kernel_launch(void* const* d_in, const int* in_sizes, int n_in,
                              void* d_out, int out_size, void* d_ws, size_t ws_size,
                              hipStream_t stream) {
    const float* ent_emb  = (const float*)d_in[0];
    const int*   proj_ids = (const int*)  d_in[1];
    const float* rel_tran = (const float*)d_in[2];
    const float* rel_bias = (const float*)d_in[3];
    const float* ln_w     = (const float*)d_in[4];
    const float* ln_b     = (const float*)d_in[5];
    float* out = (float*)d_out;

    const int B = in_sizes[1];                 // 8192 rows, one wave each
    const int blocks = (B * 64 + 255) / 256;   // 4 waves (rows) per block

    wproj_wave_kernel<<<blocks, 256, 0, stream>>>(ent_emb, proj_ids, rel_tran, rel_bias,
                                                  ln_w, ln_b, out, B);
}

// Round 7
// 99.971 us; speedup vs baseline: 4.2660x; 4.2660x over previous
//
#include <hip/hip_runtime.h>

#define ENT_GRID 16
#define ENT_DIM  64
#define EMB      1024   // ENT_GRID * ENT_DIM
#define LN_EPS   1e-5f

// ---------- sort-by-relation-id machinery (device-side, capture-safe) ----------

__global__ void zero_hist_kernel(int* __restrict__ hist, int n) {
    int i = blockIdx.x * blockDim.x + threadIdx.x;
    if (i < n) hist[i] = 0;
}

__global__ void hist_kernel(const int* __restrict__ ids, int* __restrict__ hist, int B) {
    int i = blockIdx.x * blockDim.x + threadIdx.x;
    if (i < B) atomicAdd(&hist[ids[i]], 1);
}

__global__ __launch_bounds__(1024)
void scan_kernel(const int* __restrict__ hist, int* __restrict__ cursor, int n) {
    const int t = threadIdx.x;
    const int ITEMS = (n + 1023) / 1024;
    int vals[8];
    int lsum = 0;
#pragma unroll
    for (int k = 0; k < 8; ++k) {
        int i = t * ITEMS + k;
        int v = (k < ITEMS && i < n) ? hist[i] : 0;
        vals[k] = v;
        lsum += v;
    }
    __shared__ int s[1024];
    s[t] = lsum;
    __syncthreads();
    for (int off = 1; off < 1024; off <<= 1) {
        int v = (t >= off) ? s[t - off] : 0;
        __syncthreads();
        s[t] += v;
        __syncthreads();
    }
    int run = s[t] - lsum;
#pragma unroll
    for (int k = 0; k < 8; ++k) {
        int i = t * ITEMS + k;
        if (k < ITEMS && i < n) cursor[i] = run;
        run += vals[k];
    }
}

__global__ void scatter_kernel(const int* __restrict__ ids, int* __restrict__ cursor,
                               int* __restrict__ perm, int B) {
    int i = blockIdx.x * blockDim.x + threadIdx.x;
    if (i < B) {
        int pos = atomicAdd(&cursor[ids[i]], 1);
        perm[pos] = i;
    }
    // after: cursor[r] == END offset of group r; start = cursor[r] - hist[r]
}

__device__ __forceinline__ float dot4(float4 a, float4 b) {
    return a.x * b.x + a.y * b.y + a.z * b.z + a.w * b.w;
}

// ---------- kernel A: projection, 4 blocks per relation, ZERO barriers ----------
// Block (r, q=blk&3) owns outputs i in [256q, 256q+256). Thread t: tran row
// i = 256q+t in 16 VGPR (wave reads 16 KiB contiguous). Per batch row of the
// group: e-block d=i>>4 via L1-broadcast loads, x -> d_out (unnormalized),
// per-wave LN partials (shfl butterfly) -> part[b][q*4+w]. No LDS, no syncs.
__global__ __launch_bounds__(256, 8)
void wproj_quarter_kernel(const float* __restrict__ ent_emb,
                          const float* __restrict__ rel_tran,
                          const float* __restrict__ rel_bias,
                          const int*   __restrict__ hist,
                          const int*   __restrict__ cursor_end,
                          const int*   __restrict__ perm,
                          float* __restrict__ xout,
                          float2* __restrict__ part) {
    const int blk = blockIdx.x;
    const int r   = blk >> 2;
    const int q   = blk & 3;
    const int cnt = hist[r];
    if (cnt == 0) return;
    const int start = cursor_end[r] - cnt;
    const int t = threadIdx.x;
    const int w = t >> 6;
    const int i = q * 256 + t;          // output index in [0,1024)
    const int d = i >> 4;               // e-block index

    const float4* __restrict__ tr4 = reinterpret_cast<const float4*>(
        rel_tran + (size_t)r * (ENT_DIM * ENT_GRID * ENT_GRID) + (size_t)i * ENT_GRID);
    const float4 a0 = tr4[0], a1 = tr4[1], a2 = tr4[2], a3 = tr4[3];
    const float bv = rel_bias[(size_t)r * EMB + i];

    for (int j = 0; j < cnt; ++j) {
        const int b = perm[start + j];
        const float4* __restrict__ e4 =
            reinterpret_cast<const float4*>(ent_emb + (size_t)b * EMB + d * ENT_GRID);
        const float4 e0 = e4[0], e1 = e4[1], e2 = e4[2], e3 = e4[3];

        const float x = bv + dot4(a0, e0) + dot4(a1, e1) + dot4(a2, e2) + dot4(a3, e3);
        xout[(size_t)b * EMB + i] = x;          // fire & forget

        float s = x, ss = x * x;
#pragma unroll
        for (int off = 32; off > 0; off >>= 1) {
            s  += __shfl_xor(s, off, 64);
            ss += __shfl_xor(ss, off, 64);
        }
        if ((t & 63) == 0) part[(size_t)b * 16 + q * 4 + w] = make_float2(s, ss);
    }
}

// ---------- kernel B: in-place LayerNorm over d_out rows ----------
__global__ __launch_bounds__(256, 8)
void ln_kernel(const float2* __restrict__ part,
               const float*  __restrict__ ln_w,
               const float*  __restrict__ ln_b,
               float* __restrict__ out) {
    const int b = blockIdx.x;
    const int t = threadIdx.x;
    __shared__ float sstat[2];

    if (t < 64) {
        float s = 0.0f, ss = 0.0f;
        if (t < 16) { const float2 p = part[(size_t)b * 16 + t]; s = p.x; ss = p.y; }
#pragma unroll
        for (int off = 8; off > 0; off >>= 1) {
            s  += __shfl_xor(s, off, 64);
            ss += __shfl_xor(ss, off, 64);
        }
        if (t == 0) {
            const float mu  = s * (1.0f / (float)EMB);
            const float var = ss * (1.0f / (float)EMB) - mu * mu;
            sstat[0] = mu;
            sstat[1] = rsqrtf(var + LN_EPS);
        }
    }
    __syncthreads();
    const float mu = sstat[0], rstd = sstat[1];

    float4* __restrict__ o4 = reinterpret_cast<float4*>(out + (size_t)b * EMB);
    const float4 x  = o4[t];
    const float4 w  = reinterpret_cast<const float4*>(ln_w)[t];
    const float4 bb = reinterpret_cast<const float4*>(ln_b)[t];
    float4 o;
    o.x = (x.x - mu) * rstd * w.x + bb.x;
    o.y = (x.y - mu) * rstd * w.y + bb.y;
    o.z = (x.z - mu) * rstd * w.z + bb.z;
    o.w = (x.w - mu) * rstd * w.w + bb.w;
    o4[t] = o;
}

extern "C" void kernel_launch(void* const* d_in, const int* in_sizes, int n_in,
                              void* d_out, int out_size, void* d_ws, size_t ws_size,
                              hipStream_t stream) {
    const float* ent_emb  = (const float*)d_in[0];
    const int*   proj_ids = (const int*)  d_in[1];
    const float* rel_tran = (const float*)d_in[2];
    const float* rel_bias = (const float*)d_in[3];
    const float* ln_w     = (const float*)d_in[4];
    const float* ln_b     = (const float*)d_in[5];
    float* out = (float*)d_out;

    const int B  = in_sizes[1];                                     // 8192
    const int NR = in_sizes[2] / (ENT_DIM * ENT_GRID * ENT_GRID);   // 5000

    int* w      = (int*)d_ws;
    int* hist   = w;            // [NR]
    int* cursor = w + NR;       // [NR]
    int* perm   = w + 2 * NR;   // [B]
    // float2 partials after the int arrays, 16-byte aligned
    size_t int_bytes = (size_t)(2 * NR + B) * sizeof(int);
    int_bytes = (int_bytes + 15) & ~(size_t)15;
    float2* part = (float2*)((char*)d_ws + int_bytes);   // [B*16]

    zero_hist_kernel<<<(NR + 255) / 256, 256, 0, stream>>>(hist, NR);
    hist_kernel<<<(B + 255) / 256, 256, 0, stream>>>(proj_ids, hist, B);
    scan_kernel<<<1, 1024, 0, stream>>>(hist, cursor, NR);
    scatter_kernel<<<(B + 255) / 256, 256, 0, stream>>>(proj_ids, cursor, perm, B);

    wproj_quarter_kernel<<<NR * 4, 256, 0, stream>>>(ent_emb, rel_tran, rel_bias,
                                                     hist, cursor, perm, out, part);
    ln_kernel<<<B, 256, 0, stream>>>(part, ln_w, ln_b, out);
}